// Round 3
// baseline (104.590 us; speedup 1.0000x reference)
//
#include <hip/hip_runtime.h>
#include <math.h>

#define NROWS 4096
#define LMAX 256
#define KDIM 256

// ---------------- Pass 1: masked softmax -> packed (w, idx); zero out ------
__global__ __launch_bounds__(256) void pass1_softmax(
    const float* __restrict__ w1,
    const float* __restrict__ w2,
    const int*   __restrict__ neigh_idx,
    const int*   __restrict__ lengths,
    float2*      __restrict__ pack,     // [NROWS*LMAX] (w, idx-bits)
    float*       __restrict__ out)      // zeroed here for pass2 atomics
{
    const int n   = blockIdx.x;
    const int tid = threadIdx.x;

    __shared__ float s_red[4];
    __shared__ float s_b;

    const int len = lengths[n];

    float v = -INFINITY;
    if (tid < len) v = w1[(size_t)n * LMAX + tid] + w2[(size_t)n * LMAX + tid];
    const int idx = neigh_idx[(size_t)n * LMAX + tid];

    // block max
    float m = v;
    #pragma unroll
    for (int off = 32; off >= 1; off >>= 1)
        m = fmaxf(m, __shfl_down(m, off, 64));
    if ((tid & 63) == 0) s_red[tid >> 6] = m;
    __syncthreads();
    if (tid == 0)
        s_b = fmaxf(fmaxf(s_red[0], s_red[1]), fmaxf(s_red[2], s_red[3]));
    __syncthreads();
    m = s_b;

    // block sum of exp
    const float e = (tid < len) ? __expf(v - m) : 0.0f;
    float s = e;
    #pragma unroll
    for (int off = 32; off >= 1; off >>= 1)
        s += __shfl_down(s, off, 64);
    if ((tid & 63) == 0) s_red[tid >> 6] = s;
    __syncthreads();
    if (tid == 0) s_b = s_red[0] + s_red[1] + s_red[2] + s_red[3];
    __syncthreads();

    const float w = e * (1.0f / s_b);        // 0 for tid >= len
    pack[(size_t)n * LMAX + tid] = make_float2(w, __int_as_float(idx));

    if (tid == 0) out[n] = 0.0f;
}

// ---------------- Pass 2: K-chunked gather-dot with XCD affinity ----------
// cell = (blockIdx%8) + PHASE*8 owns table floats [cell*16, cell*16+16).
// Chunk-slice footprint = 50000*64B = 3.2MB < 4MiB per-XCD L2.
// One wave handles one n; 16 pairs per memory instruction (4 lanes/pair).
template<int PHASE>
__global__ __launch_bounds__(256) void pass2_gather(
    const float*  __restrict__ table,
    const int*    __restrict__ cand_idx,
    const int*    __restrict__ lengths,
    const float2* __restrict__ pack,
    float*        __restrict__ out)
{
    const int cell  = (blockIdx.x & 7) + PHASE * 8;   // K-chunk 0..15
    const int group = blockIdx.x >> 3;                // n-group of 4
    const int wave  = threadIdx.x >> 6;
    const int lane  = threadIdx.x & 63;
    const int n     = group * 4 + wave;

    const int len   = lengths[n];
    const int kbase = cell * 16 + (lane & 3) * 4;     // this lane's float4
    const int slot  = lane >> 2;                      // pair slot 0..15

    // candidate fragment: one 64B line per wave, lane-broadcast within it
    const float4 c4 = *(const float4*)&table[(size_t)cand_idx[n] * KDIM + kbase];

    const float2* prow = pack + (size_t)n * LMAX;
    float acc0 = 0.0f, acc1 = 0.0f;

    int l0 = 0;
    // main loop: 32 pairs per iteration, guard-free (slot < 16)
    for (; l0 + 32 <= len; l0 += 32) {
        const float2 p0 = prow[l0 + slot];
        const float2 p1 = prow[l0 + 16 + slot];
        const int i0 = __float_as_int(p0.y);
        const int i1 = __float_as_int(p1.y);
        const float4 t0 = *(const float4*)&table[(size_t)i0 * KDIM + kbase];
        const float4 t1 = *(const float4*)&table[(size_t)i1 * KDIM + kbase];
        acc0 = fmaf(p0.x, t0.x*c4.x + t0.y*c4.y + t0.z*c4.z + t0.w*c4.w, acc0);
        acc1 = fmaf(p1.x, t1.x*c4.x + t1.y*c4.y + t1.z*c4.z + t1.w*c4.w, acc1);
    }
    // tail: 16 pairs per iteration, guarded
    for (; l0 < len; l0 += 16) {
        const int l = l0 + slot;
        if (l < len) {
            const float2 p = prow[l];
            const int   i = __float_as_int(p.y);
            const float4 t = *(const float4*)&table[(size_t)i * KDIM + kbase];
            acc0 = fmaf(p.x, t.x*c4.x + t.y*c4.y + t.z*c4.z + t.w*c4.w, acc0);
        }
    }

    float acc = acc0 + acc1;
    #pragma unroll
    for (int off = 32; off >= 1; off >>= 1)
        acc += __shfl_down(acc, off, 64);
    if (lane == 0) atomicAdd(&out[n], acc);
}

extern "C" void kernel_launch(void* const* d_in, const int* in_sizes, int n_in,
                              void* d_out, int out_size, void* d_ws, size_t ws_size,
                              hipStream_t stream) {
    const float* table     = (const float*)d_in[0];
    const float* w1        = (const float*)d_in[1];
    const float* w2        = (const float*)d_in[2];
    const int*   cand_idx  = (const int*)d_in[3];
    const int*   neigh_idx = (const int*)d_in[4];
    const int*   lengths   = (const int*)d_in[5];
    float*  out  = (float*)d_out;
    float2* pack = (float2*)d_ws;      // 4096*256*8B = 8 MB scratch

    pass1_softmax<<<NROWS, 256, 0, stream>>>(w1, w2, neigh_idx, lengths,
                                             pack, out);
    // chunks 0..7: XCD x caches table columns [x*16, x*16+16) (3.2 MB)
    pass2_gather<0><<<(NROWS / 4) * 8, 256, 0, stream>>>(table, cand_idx,
                                                         lengths, pack, out);
    // chunks 8..15
    pass2_gather<1><<<(NROWS / 4) * 8, 256, 0, stream>>>(table, cand_idx,
                                                         lengths, pack, out);
}

// Round 4
// 75.242 us; speedup vs baseline: 1.3900x; 1.3900x over previous
//
#include <hip/hip_runtime.h>
#include <hip/hip_fp16.h>
#include <math.h>

#define NROWS 4096
#define LMAX 256
#define KDIM 256
#define NREL 50000
#define NCELL 8                      // K-chunks == XCDs; 32 cols (64B fp16) each

#define TBR_ELEMS ((size_t)NCELL * NREL * 32)            // fp16 elements
#define TBR_BYTES (TBR_ELEMS * 2)                        // 25,600,000
#define META_BYTES ((size_t)NROWS * LMAX * 4)            // 4,194,304

// ---------- Kernel A: fp32 table -> chunk-major fp16 tBR[8][NREL][32] ------
__global__ __launch_bounds__(256) void convert_kernel(
    const float* __restrict__ table, __half* __restrict__ tBR)
{
    const int r  = blockIdx.x * 8 + (threadIdx.x >> 5);   // row 0..49999
    const int k0 = (threadIdx.x & 31) * 8;                // col block of 8
    const float4* src = (const float4*)&table[(size_t)r * KDIM + k0];
    const float4 f0 = src[0];
    const float4 f1 = src[1];
    __half2 h[4];
    h[0] = __floats2half2_rn(f0.x, f0.y);
    h[1] = __floats2half2_rn(f0.z, f0.w);
    h[2] = __floats2half2_rn(f1.x, f1.y);
    h[3] = __floats2half2_rn(f1.z, f1.w);
    const int c  = k0 >> 5;                               // chunk 0..7
    const int kk = k0 & 31;
    __half* dst = tBR + ((size_t)c * NREL + r) * 32 + kk;
    *(uint4*)dst = *(const uint4*)h;
}

// ---------- Kernel B: masked softmax -> meta (idx<<16 | fp16(w)); zero out -
__global__ __launch_bounds__(256) void pass1_softmax(
    const float* __restrict__ w1,
    const float* __restrict__ w2,
    const int*   __restrict__ neigh_idx,
    const int*   __restrict__ lengths,
    unsigned*    __restrict__ meta,
    float*       __restrict__ out)
{
    const int n   = blockIdx.x;
    const int tid = threadIdx.x;

    __shared__ float s_red[4];
    __shared__ float s_b;

    const int len = lengths[n];

    float v = -INFINITY;
    if (tid < len) v = w1[(size_t)n * LMAX + tid] + w2[(size_t)n * LMAX + tid];
    const int idx = neigh_idx[(size_t)n * LMAX + tid];

    float m = v;
    #pragma unroll
    for (int off = 32; off >= 1; off >>= 1)
        m = fmaxf(m, __shfl_down(m, off, 64));
    if ((tid & 63) == 0) s_red[tid >> 6] = m;
    __syncthreads();
    if (tid == 0)
        s_b = fmaxf(fmaxf(s_red[0], s_red[1]), fmaxf(s_red[2], s_red[3]));
    __syncthreads();
    m = s_b;

    const float e = (tid < len) ? __expf(v - m) : 0.0f;
    float s = e;
    #pragma unroll
    for (int off = 32; off >= 1; off >>= 1)
        s += __shfl_down(s, off, 64);
    if ((tid & 63) == 0) s_red[tid >> 6] = s;
    __syncthreads();
    if (tid == 0) s_b = s_red[0] + s_red[1] + s_red[2] + s_red[3];
    __syncthreads();

    const float w = e * (1.0f / s_b);                      // 0 for tid >= len
    const unsigned wb = (unsigned)__half_as_ushort(__float2half_rn(w));
    meta[(size_t)n * LMAX + tid] = ((unsigned)idx << 16) | wb;

    if (tid == 0) out[n] = 0.0f;
}

// ---------- Kernel C: single-phase XCD-affine gather-dot -------------------
__global__ __launch_bounds__(256) void gather_kernel(
    const float*    __restrict__ table,     // fp32, for candidate fragment
    const __half*   __restrict__ tBR,
    const int*      __restrict__ cand_idx,
    const int*      __restrict__ lengths,
    const unsigned* __restrict__ meta,
    float*          __restrict__ out)
{
    const int cell = blockIdx.x & 7;                       // -> XCD (RR)
    const int n    = (blockIdx.x >> 3) * 4 + (threadIdx.x >> 6);
    const int lane = threadIdx.x & 63;
    const int slot = lane >> 2;                            // pair slot 0..15
    const int q    = lane & 3;                             // 8-col quarter
    const int len  = lengths[n];

    // candidate fragment: fp32, 8 cols of this (cell, q)
    const float* crow = &table[(size_t)cand_idx[n] * KDIM + cell * 32 + q * 8];
    const float4 c0 = *(const float4*)crow;
    const float4 c1 = *(const float4*)(crow + 4);

    const unsigned* mrow  = meta + (size_t)n * LMAX;
    const __half*   gbase = tBR + (size_t)cell * NREL * 32 + q * 8;

    float acc = 0.0f;
    for (int l0 = 0; l0 < len; l0 += 16) {                 // branchless: w=0 pad
        const unsigned mv = __builtin_nontemporal_load(&mrow[l0 + slot]);
        const int   idx = mv >> 16;
        const float w   = __half2float(__ushort_as_half((unsigned short)(mv & 0xffffu)));
        const uint4 t   = *(const uint4*)(gbase + (size_t)idx * 32);
        const __half2* th = (const __half2*)&t;
        const float2 f0 = __half22float2(th[0]);
        const float2 f1 = __half22float2(th[1]);
        const float2 f2 = __half22float2(th[2]);
        const float2 f3 = __half22float2(th[3]);
        float s;
        s = f0.x * c0.x;
        s = fmaf(f0.y, c0.y, s);
        s = fmaf(f1.x, c0.z, s);
        s = fmaf(f1.y, c0.w, s);
        s = fmaf(f2.x, c1.x, s);
        s = fmaf(f2.y, c1.y, s);
        s = fmaf(f3.x, c1.z, s);
        s = fmaf(f3.y, c1.w, s);
        acc = fmaf(w, s, acc);
    }

    #pragma unroll
    for (int off = 32; off >= 1; off >>= 1)
        acc += __shfl_down(acc, off, 64);
    if (lane == 0) atomicAdd(&out[n], acc);
}

// ---------- Fallback (R1 kernel) if ws too small ---------------------------
__global__ __launch_bounds__(256) void epanre_fallback(
    const float* __restrict__ table,
    const float* __restrict__ w1,
    const float* __restrict__ w2,
    const int*   __restrict__ cand_idx,
    const int*   __restrict__ neigh_idx,
    const int*   __restrict__ lengths,
    float*       __restrict__ out)
{
    const int n   = blockIdx.x;
    const int tid = threadIdx.x;

    __shared__ __align__(16) float s_w[LMAX];
    __shared__ int   s_idx[LMAX];
    __shared__ __align__(16) float s_cand[KDIM];
    __shared__ float s_red[4];
    __shared__ float s_bcast;

    const int len = lengths[n];

    float v = -INFINITY;
    if (tid < len) v = w1[(size_t)n * LMAX + tid] + w2[(size_t)n * LMAX + tid];
    s_idx[tid]  = neigh_idx[(size_t)n * LMAX + tid];
    s_cand[tid] = table[(size_t)cand_idx[n] * KDIM + tid];

    float m = v;
    #pragma unroll
    for (int off = 32; off >= 1; off >>= 1)
        m = fmaxf(m, __shfl_down(m, off, 64));
    if ((tid & 63) == 0) s_red[tid >> 6] = m;
    __syncthreads();
    if (tid == 0)
        s_bcast = fmaxf(fmaxf(s_red[0], s_red[1]), fmaxf(s_red[2], s_red[3]));
    __syncthreads();
    m = s_bcast;

    float e = (tid < len) ? __expf(v - m) : 0.0f;
    float s = e;
    #pragma unroll
    for (int off = 32; off >= 1; off >>= 1)
        s += __shfl_down(s, off, 64);
    if ((tid & 63) == 0) s_red[tid >> 6] = s;
    __syncthreads();
    if (tid == 0) s_bcast = s_red[0] + s_red[1] + s_red[2] + s_red[3];
    __syncthreads();
    const float inv = 1.0f / s_bcast;
    s_w[tid] = e * inv;
    __syncthreads();

    const int g    = tid >> 6;
    const int lane = tid & 63;
    const float4* tab4 = (const float4*)table;
    float4 acc = make_float4(0.f, 0.f, 0.f, 0.f);

    for (int l0 = 0; l0 < len; l0 += 4) {
        const int   l = l0 + g;
        const float w = (l < len) ? s_w[l] : 0.0f;
        const int   idx = s_idx[l];
        const float4 t = tab4[(size_t)idx * (KDIM / 4) + lane];
        acc.x = fmaf(w, t.x, acc.x);
        acc.y = fmaf(w, t.y, acc.y);
        acc.z = fmaf(w, t.z, acc.z);
        acc.w = fmaf(w, t.w, acc.w);
    }

    const float4 c = ((const float4*)s_cand)[lane];
    float partial = acc.x * c.x + acc.y * c.y + acc.z * c.z + acc.w * c.w;
    #pragma unroll
    for (int off = 32; off >= 1; off >>= 1)
        partial += __shfl_down(partial, off, 64);
    if (lane == 0) s_red[g] = partial;
    __syncthreads();
    if (tid == 0) out[n] = s_red[0] + s_red[1] + s_red[2] + s_red[3];
}

extern "C" void kernel_launch(void* const* d_in, const int* in_sizes, int n_in,
                              void* d_out, int out_size, void* d_ws, size_t ws_size,
                              hipStream_t stream) {
    const float* table     = (const float*)d_in[0];
    const float* w1        = (const float*)d_in[1];
    const float* w2        = (const float*)d_in[2];
    const int*   cand_idx  = (const int*)d_in[3];
    const int*   neigh_idx = (const int*)d_in[4];
    const int*   lengths   = (const int*)d_in[5];
    float* out = (float*)d_out;

    if (ws_size < TBR_BYTES + META_BYTES) {
        epanre_fallback<<<NROWS, 256, 0, stream>>>(table, w1, w2, cand_idx,
                                                   neigh_idx, lengths, out);
        return;
    }

    __half*   tBR  = (__half*)d_ws;
    unsigned* meta = (unsigned*)((char*)d_ws + TBR_BYTES);

    convert_kernel<<<NREL / 8, 256, 0, stream>>>(table, tBR);
    pass1_softmax<<<NROWS, 256, 0, stream>>>(w1, w2, neigh_idx, lengths,
                                             meta, out);
    gather_kernel<<<(NROWS / 4) * NCELL, 256, 0, stream>>>(table, tBR,
                                                           cand_idx, lengths,
                                                           meta, out);
}

// Round 5
// 53.044 us; speedup vs baseline: 1.9718x; 1.4185x over previous
//
#include <hip/hip_runtime.h>
#include <hip/hip_fp16.h>
#include <math.h>

#define NROWS 4096
#define LMAX 256
#define KDIM 256
#define NREL 50000
#define NCELL 8                      // K-chunks == XCDs; 32 cols (64B fp16) each

#define TBR_ELEMS ((size_t)NCELL * NREL * 32)            // fp16 elements
#define TBR_BYTES (TBR_ELEMS * 2)                        // 25,600,000
#define META_BYTES ((size_t)NROWS * LMAX * 4)            // 4,194,304
#define ROWS_PER_BLK 64

// ---------- Kernel A: XCD-affine convert: cell c handles table cols --------
// [32c, 32c+32) only -> writes land dirty in cell c's (local) L2.
__global__ __launch_bounds__(256) void convert_kernel(
    const float* __restrict__ table, __half* __restrict__ tBR)
{
    const int cell = blockIdx.x & 7;                      // -> XCD (RR)
    const int rg   = blockIdx.x >> 3;
    const int r    = rg * ROWS_PER_BLK + (threadIdx.x >> 2);
    if (r >= NREL) return;
    const int q    = threadIdx.x & 3;                     // 8-col quarter

    const float4* src =
        (const float4*)&table[(size_t)r * KDIM + cell * 32 + q * 8];
    const float4 f0 = src[0];
    const float4 f1 = src[1];
    __half2 h[4];
    h[0] = __floats2half2_rn(f0.x, f0.y);
    h[1] = __floats2half2_rn(f0.z, f0.w);
    h[2] = __floats2half2_rn(f1.x, f1.y);
    h[3] = __floats2half2_rn(f1.z, f1.w);
    __half* dst = tBR + ((size_t)cell * NREL + r) * 32 + q * 8;
    *(uint4*)dst = *(const uint4*)h;
}

// ---------- Kernel B: masked softmax -> meta (idx<<16 | fp16(w)); zero out -
__global__ __launch_bounds__(256) void pass1_softmax(
    const float* __restrict__ w1,
    const float* __restrict__ w2,
    const int*   __restrict__ neigh_idx,
    const int*   __restrict__ lengths,
    unsigned*    __restrict__ meta,
    float*       __restrict__ out)
{
    const int n   = blockIdx.x;
    const int tid = threadIdx.x;

    __shared__ float s_red[4];
    __shared__ float s_b;

    const int len = lengths[n];

    float v = -INFINITY;
    if (tid < len) v = w1[(size_t)n * LMAX + tid] + w2[(size_t)n * LMAX + tid];
    const int idx = neigh_idx[(size_t)n * LMAX + tid];

    float m = v;
    #pragma unroll
    for (int off = 32; off >= 1; off >>= 1)
        m = fmaxf(m, __shfl_down(m, off, 64));
    if ((tid & 63) == 0) s_red[tid >> 6] = m;
    __syncthreads();
    if (tid == 0)
        s_b = fmaxf(fmaxf(s_red[0], s_red[1]), fmaxf(s_red[2], s_red[3]));
    __syncthreads();
    m = s_b;

    const float e = (tid < len) ? __expf(v - m) : 0.0f;
    float s = e;
    #pragma unroll
    for (int off = 32; off >= 1; off >>= 1)
        s += __shfl_down(s, off, 64);
    if ((tid & 63) == 0) s_red[tid >> 6] = s;
    __syncthreads();
    if (tid == 0) s_b = s_red[0] + s_red[1] + s_red[2] + s_red[3];
    __syncthreads();

    const float w = e * (1.0f / s_b);                      // 0 for tid >= len
    const unsigned wb = (unsigned)__half_as_ushort(__float2half_rn(w));
    meta[(size_t)n * LMAX + tid] = ((unsigned)idx << 16) | wb;

    if (tid == 0) out[n] = 0.0f;
}

// ---------- Kernel C: XCD-affine gather-dot, LDS meta, MLP=4 ---------------
__global__ __launch_bounds__(256) void gather_kernel(
    const float*    __restrict__ table,     // fp32, for candidate fragment
    const __half*   __restrict__ tBR,
    const int*      __restrict__ cand_idx,
    const int*      __restrict__ lengths,
    const unsigned* __restrict__ meta,
    float*          __restrict__ out)
{
    const int cell = blockIdx.x & 7;                       // -> XCD (RR)
    const int wv   = threadIdx.x >> 6;
    const int n    = (blockIdx.x >> 3) * 4 + wv;
    const int lane = threadIdx.x & 63;
    const int slot = lane >> 2;                            // pair slot 0..15
    const int q    = lane & 3;                             // 8-col quarter
    const int len  = lengths[n];

    __shared__ unsigned s_meta[4][LMAX];

    // stage this wave's whole meta row (1KB) into LDS: one uint4 per lane
    {
        const uint4 mv = *(const uint4*)&meta[(size_t)n * LMAX + lane * 4];
        *(uint4*)&s_meta[wv][lane * 4] = mv;
    }

    // candidate fragment: fp32, 8 cols of this (cell, q)
    const float* crow = &table[(size_t)cand_idx[n] * KDIM + cell * 32 + q * 8];
    const float4 c0 = *(const float4*)crow;
    const float4 c1 = *(const float4*)(crow + 4);

    __syncthreads();

    const __half* gbase = tBR + (size_t)cell * NREL * 32 + q * 8;
    const unsigned* sm = s_meta[wv];

    float a0 = 0.f, a1 = 0.f, a2 = 0.f, a3 = 0.f;
    const int len16 = (len + 15) & ~15;                    // 16..256
    int l0 = 0;

    // main: 64 pairs per superiter, 4 independent 64B gathers in flight
    for (; l0 + 64 <= len16; l0 += 64) {
        const unsigned m0 = sm[l0      + slot];
        const unsigned m1 = sm[l0 + 16 + slot];
        const unsigned m2 = sm[l0 + 32 + slot];
        const unsigned m3 = sm[l0 + 48 + slot];
        const uint4 t0 = *(const uint4*)(gbase + (size_t)(m0 >> 16) * 32);
        const uint4 t1 = *(const uint4*)(gbase + (size_t)(m1 >> 16) * 32);
        const uint4 t2 = *(const uint4*)(gbase + (size_t)(m2 >> 16) * 32);
        const uint4 t3 = *(const uint4*)(gbase + (size_t)(m3 >> 16) * 32);
        {
            const __half2* th = (const __half2*)&t0;
            const float2 f0 = __half22float2(th[0]);
            const float2 f1 = __half22float2(th[1]);
            const float2 f2 = __half22float2(th[2]);
            const float2 f3 = __half22float2(th[3]);
            float s = f0.x * c0.x;
            s = fmaf(f0.y, c0.y, s); s = fmaf(f1.x, c0.z, s);
            s = fmaf(f1.y, c0.w, s); s = fmaf(f2.x, c1.x, s);
            s = fmaf(f2.y, c1.y, s); s = fmaf(f3.x, c1.z, s);
            s = fmaf(f3.y, c1.w, s);
            a0 = fmaf(__half2float(__ushort_as_half((unsigned short)(m0 & 0xffffu))), s, a0);
        }
        {
            const __half2* th = (const __half2*)&t1;
            const float2 f0 = __half22float2(th[0]);
            const float2 f1 = __half22float2(th[1]);
            const float2 f2 = __half22float2(th[2]);
            const float2 f3 = __half22float2(th[3]);
            float s = f0.x * c0.x;
            s = fmaf(f0.y, c0.y, s); s = fmaf(f1.x, c0.z, s);
            s = fmaf(f1.y, c0.w, s); s = fmaf(f2.x, c1.x, s);
            s = fmaf(f2.y, c1.y, s); s = fmaf(f3.x, c1.z, s);
            s = fmaf(f3.y, c1.w, s);
            a1 = fmaf(__half2float(__ushort_as_half((unsigned short)(m1 & 0xffffu))), s, a1);
        }
        {
            const __half2* th = (const __half2*)&t2;
            const float2 f0 = __half22float2(th[0]);
            const float2 f1 = __half22float2(th[1]);
            const float2 f2 = __half22float2(th[2]);
            const float2 f3 = __half22float2(th[3]);
            float s = f0.x * c0.x;
            s = fmaf(f0.y, c0.y, s); s = fmaf(f1.x, c0.z, s);
            s = fmaf(f1.y, c0.w, s); s = fmaf(f2.x, c1.x, s);
            s = fmaf(f2.y, c1.y, s); s = fmaf(f3.x, c1.z, s);
            s = fmaf(f3.y, c1.w, s);
            a2 = fmaf(__half2float(__ushort_as_half((unsigned short)(m2 & 0xffffu))), s, a2);
        }
        {
            const __half2* th = (const __half2*)&t3;
            const float2 f0 = __half22float2(th[0]);
            const float2 f1 = __half22float2(th[1]);
            const float2 f2 = __half22float2(th[2]);
            const float2 f3 = __half22float2(th[3]);
            float s = f0.x * c0.x;
            s = fmaf(f0.y, c0.y, s); s = fmaf(f1.x, c0.z, s);
            s = fmaf(f1.y, c0.w, s); s = fmaf(f2.x, c1.x, s);
            s = fmaf(f2.y, c1.y, s); s = fmaf(f3.x, c1.z, s);
            s = fmaf(f3.y, c1.w, s);
            a3 = fmaf(__half2float(__ushort_as_half((unsigned short)(m3 & 0xffffu))), s, a3);
        }
    }
    // remainder: 16 pairs per iter (w=0 padding keeps it branchless)
    for (; l0 < len16; l0 += 16) {
        const unsigned mv = sm[l0 + slot];
        const uint4 t = *(const uint4*)(gbase + (size_t)(mv >> 16) * 32);
        const __half2* th = (const __half2*)&t;
        const float2 f0 = __half22float2(th[0]);
        const float2 f1 = __half22float2(th[1]);
        const float2 f2 = __half22float2(th[2]);
        const float2 f3 = __half22float2(th[3]);
        float s = f0.x * c0.x;
        s = fmaf(f0.y, c0.y, s); s = fmaf(f1.x, c0.z, s);
        s = fmaf(f1.y, c0.w, s); s = fmaf(f2.x, c1.x, s);
        s = fmaf(f2.y, c1.y, s); s = fmaf(f3.x, c1.z, s);
        s = fmaf(f3.y, c1.w, s);
        a0 = fmaf(__half2float(__ushort_as_half((unsigned short)(mv & 0xffffu))), s, a0);
    }

    float acc = (a0 + a1) + (a2 + a3);
    #pragma unroll
    for (int off = 32; off >= 1; off >>= 1)
        acc += __shfl_down(acc, off, 64);
    if (lane == 0) atomicAdd(&out[n], acc);
}

// ---------- Fallback (R1 kernel) if ws too small ---------------------------
__global__ __launch_bounds__(256) void epanre_fallback(
    const float* __restrict__ table,
    const float* __restrict__ w1,
    const float* __restrict__ w2,
    const int*   __restrict__ cand_idx,
    const int*   __restrict__ neigh_idx,
    const int*   __restrict__ lengths,
    float*       __restrict__ out)
{
    const int n   = blockIdx.x;
    const int tid = threadIdx.x;

    __shared__ __align__(16) float s_w[LMAX];
    __shared__ int   s_idx[LMAX];
    __shared__ __align__(16) float s_cand[KDIM];
    __shared__ float s_red[4];
    __shared__ float s_bcast;

    const int len = lengths[n];

    float v = -INFINITY;
    if (tid < len) v = w1[(size_t)n * LMAX + tid] + w2[(size_t)n * LMAX + tid];
    s_idx[tid]  = neigh_idx[(size_t)n * LMAX + tid];
    s_cand[tid] = table[(size_t)cand_idx[n] * KDIM + tid];

    float m = v;
    #pragma unroll
    for (int off = 32; off >= 1; off >>= 1)
        m = fmaxf(m, __shfl_down(m, off, 64));
    if ((tid & 63) == 0) s_red[tid >> 6] = m;
    __syncthreads();
    if (tid == 0)
        s_bcast = fmaxf(fmaxf(s_red[0], s_red[1]), fmaxf(s_red[2], s_red[3]));
    __syncthreads();
    m = s_bcast;

    float e = (tid < len) ? __expf(v - m) : 0.0f;
    float s = e;
    #pragma unroll
    for (int off = 32; off >= 1; off >>= 1)
        s += __shfl_down(s, off, 64);
    if ((tid & 63) == 0) s_red[tid >> 6] = s;
    __syncthreads();
    if (tid == 0) s_bcast = s_red[0] + s_red[1] + s_red[2] + s_red[3];
    __syncthreads();
    const float inv = 1.0f / s_bcast;
    s_w[tid] = e * inv;
    __syncthreads();

    const int g    = tid >> 6;
    const int lane = tid & 63;
    const float4* tab4 = (const float4*)table;
    float4 acc = make_float4(0.f, 0.f, 0.f, 0.f);

    for (int l0 = 0; l0 < len; l0 += 4) {
        const int   l = l0 + g;
        const float w = (l < len) ? s_w[l] : 0.0f;
        const int   idx = s_idx[l];
        const float4 t = tab4[(size_t)idx * (KDIM / 4) + lane];
        acc.x = fmaf(w, t.x, acc.x);
        acc.y = fmaf(w, t.y, acc.y);
        acc.z = fmaf(w, t.z, acc.z);
        acc.w = fmaf(w, t.w, acc.w);
    }

    const float4 c = ((const float4*)s_cand)[lane];
    float partial = acc.x * c.x + acc.y * c.y + acc.z * c.z + acc.w * c.w;
    #pragma unroll
    for (int off = 32; off >= 1; off >>= 1)
        partial += __shfl_down(partial, off, 64);
    if (lane == 0) s_red[g] = partial;
    __syncthreads();
    if (tid == 0) out[n] = s_red[0] + s_red[1] + s_red[2] + s_red[3];
}

extern "C" void kernel_launch(void* const* d_in, const int* in_sizes, int n_in,
                              void* d_out, int out_size, void* d_ws, size_t ws_size,
                              hipStream_t stream) {
    const float* table     = (const float*)d_in[0];
    const float* w1        = (const float*)d_in[1];
    const float* w2        = (const float*)d_in[2];
    const int*   cand_idx  = (const int*)d_in[3];
    const int*   neigh_idx = (const int*)d_in[4];
    const int*   lengths   = (const int*)d_in[5];
    float* out = (float*)d_out;

    if (ws_size < TBR_BYTES + META_BYTES) {
        epanre_fallback<<<NROWS, 256, 0, stream>>>(table, w1, w2, cand_idx,
                                                   neigh_idx, lengths, out);
        return;
    }

    __half*   tBR  = (__half*)d_ws;
    unsigned* meta = (unsigned*)((char*)d_ws + TBR_BYTES);

    const int rgs = (NREL + ROWS_PER_BLK - 1) / ROWS_PER_BLK;   // 782
    convert_kernel<<<rgs * NCELL, 256, 0, stream>>>(table, tBR);
    pass1_softmax<<<NROWS, 256, 0, stream>>>(w1, w2, neigh_idx, lengths,
                                             meta, out);
    gather_kernel<<<(NROWS / 4) * NCELL, 256, 0, stream>>>(table, tBR,
                                                           cand_idx, lengths,
                                                           meta, out);
}